// Round 1
// baseline (66.531 us; speedup 1.0000x reference)
//
#include <hip/hip_runtime.h>

// Median 3x3 pooling with reflect padding over (8,16,512,512) f32.
// Each thread computes 4 consecutive outputs in a row (float4 I/O).

#define S2(a, b) { float _t = fminf(a, b); b = fmaxf(a, b); a = _t; }

__device__ __forceinline__ float median9(float p0, float p1, float p2,
                                         float p3, float p4, float p5,
                                         float p6, float p7, float p8) {
    // Paeth 19-exchange median-of-9 network (lower median == true median, n=9)
    S2(p1, p2); S2(p4, p5); S2(p7, p8);
    S2(p0, p1); S2(p3, p4); S2(p6, p7);
    S2(p1, p2); S2(p4, p5); S2(p7, p8);
    S2(p0, p3); S2(p5, p8); S2(p4, p7);
    S2(p3, p6); S2(p1, p4); S2(p2, p5);
    S2(p4, p7); S2(p4, p2); S2(p6, p4);
    S2(p4, p2);
    return p4;
}

__global__ __launch_bounds__(256) void median3x3_kernel(
        const float* __restrict__ x, float* __restrict__ y) {
    constexpr int H = 512, W = 512;
    // 8*16 planes * 512 rows * 128 groups-of-4 = 8,388,608 threads
    const int gid   = blockIdx.x * blockDim.x + threadIdx.x;
    const int w4    = (gid & 127) << 2;   // 0..508, step 4
    const int h     = (gid >> 7) & 511;
    const int plane = gid >> 16;          // 0..127

    const float* __restrict__ p = x + (size_t)plane * (H * W);
    float* __restrict__ q       = y + (size_t)plane * (H * W) + (size_t)h * W;

    // reflect-pad row indices (pad=1, reflect: -1 -> 1, H -> H-2)
    const int hm = (h == 0)     ? 1     : h - 1;
    const int hp = (h == H - 1) ? H - 2 : h + 1;

    const float* __restrict__ r0 = p + (size_t)hm * W;
    const float* __restrict__ r1 = p + (size_t)h  * W;
    const float* __restrict__ r2 = p + (size_t)hp * W;

    // reflect-pad halo column indices
    const int wl = (w4 == 0)     ? 1     : w4 - 1;
    const int wr = (w4 == W - 4) ? W - 2 : w4 + 4;

    const float4 a0 = *reinterpret_cast<const float4*>(r0 + w4);
    const float4 a1 = *reinterpret_cast<const float4*>(r1 + w4);
    const float4 a2 = *reinterpret_cast<const float4*>(r2 + w4);
    const float l0 = r0[wl], l1 = r1[wl], l2 = r2[wl];
    const float R0 = r0[wr], R1 = r1[wr], R2 = r2[wr];

    float4 out;
    out.x = median9(l0,   a0.x, a0.y,   l1,   a1.x, a1.y,   l2,   a2.x, a2.y);
    out.y = median9(a0.x, a0.y, a0.z,   a1.x, a1.y, a1.z,   a2.x, a2.y, a2.z);
    out.z = median9(a0.y, a0.z, a0.w,   a1.y, a1.z, a1.w,   a2.y, a2.z, a2.w);
    out.w = median9(a0.z, a0.w, R0,     a1.z, a1.w, R1,     a2.z, a2.w, R2);

    *reinterpret_cast<float4*>(q + w4) = out;
}

extern "C" void kernel_launch(void* const* d_in, const int* in_sizes, int n_in,
                              void* d_out, int out_size, void* d_ws, size_t ws_size,
                              hipStream_t stream) {
    const float* x = (const float*)d_in[0];
    float* y = (float*)d_out;
    // 8*16*512*512 / 4 outputs-per-thread = 8,388,608 threads
    const int threads = 8 * 16 * 512 * (512 / 4);
    const int block = 256;
    const int grid = threads / block; // 32768
    median3x3_kernel<<<grid, block, 0, stream>>>(x, y);
}